// Round 4
// baseline (303.815 us; speedup 1.0000x reference)
//
#include <hip/hip_runtime.h>
#include <hip/hip_bf16.h>

#define NT 4096      // tokens
#define DIM 768
#define NE 1536      // experts
#define ED 64        // expert dim
#define GAP_THR 8e-3f

typedef __attribute__((ext_vector_type(8))) short short8v;
typedef __attribute__((ext_vector_type(4))) float f32x4;

__device__ __forceinline__ unsigned short f2bf(float f) {
  unsigned int u = __float_as_uint(f);
  unsigned int r = (u + 0x7fffu + ((u >> 16) & 1u)) >> 16;   // RNE
  return (unsigned short)r;
}
__device__ __forceinline__ float bf2f(unsigned short h) {
  return __uint_as_float(((unsigned int)h) << 16);
}

__device__ __forceinline__ void gload16(const void* g, void* l) {
  __builtin_amdgcn_global_load_lds((const __attribute__((address_space(1))) void*)g,
                                   (__attribute__((address_space(3))) void*)l, 16, 0, 0);
}

__device__ __forceinline__ void top2_merge(float& m1, int& i1, float& m2, int& i2,
                                           float om1, int oi1, float om2, int oi2) {
  if (om1 > m1 || (om1 == m1 && oi1 < i1)) {
    if (m1 > om2 || (m1 == om2 && i1 < oi2)) { m2 = m1; i2 = i1; }
    else { m2 = om2; i2 = oi2; }
    m1 = om1; i1 = oi1;
  } else {
    if (om1 > m2 || (om1 == m2 && oi1 < i2)) { m2 = om1; i2 = oi1; }
  }
}

// ---- Kernel 0: fp32 -> (bf16 hi, bf16 lo) split (x and gate_w); zero rc_cnt ----
// NO hipMemsetAsync anywhere: the 6KB fill node cost ~175us/replay (rocprof R3).
__global__ __launch_bounds__(256) void split_all(
    const float* __restrict__ x, const float* __restrict__ gw,
    unsigned short* __restrict__ xhi, unsigned short* __restrict__ xlo,
    unsigned short* __restrict__ ghi, unsigned short* __restrict__ glo,
    int* __restrict__ rc_cnt) {
  if (blockIdx.x == 0 && threadIdx.x == 0) *rc_cnt = 0;
  const int nx4 = NT * DIM / 4;
  const int ng4 = NE * DIM / 4;
  int i = blockIdx.x * 256 + threadIdx.x;
  const float* src; unsigned short* hi; unsigned short* lo; int j;
  if (i < nx4) { src = x; hi = xhi; lo = xlo; j = i; }
  else { j = i - nx4; if (j >= ng4) return; src = gw; hi = ghi; lo = glo; }
  float4 v = ((const float4*)src)[j];
  unsigned short h0 = f2bf(v.x), h1 = f2bf(v.y), h2 = f2bf(v.z), h3 = f2bf(v.w);
  ((ushort4*)hi)[j] = make_ushort4(h0, h1, h2, h3);
  ((ushort4*)lo)[j] = make_ushort4(f2bf(v.x - bf2f(h0)), f2bf(v.y - bf2f(h1)),
                                   f2bf(v.z - bf2f(h2)), f2bf(v.w - bf2f(h3)));
}

// ---- Kernel 1: gating GEMM (bf16x3 MFMA) + fused partial softmax ----
__global__ __launch_bounds__(256) void gate_mfma(
    const unsigned short* __restrict__ xhi, const unsigned short* __restrict__ xlo,
    const unsigned short* __restrict__ ghi, const unsigned short* __restrict__ glo,
    const float* __restrict__ gb, const float* __restrict__ noise,
    float4* __restrict__ part_a, int* __restrict__ part_i2) {
  __shared__ __align__(16) unsigned short sA[2 * 128 * 32];  // [0..4095]=hi, [4096..]=lo
  __shared__ __align__(16) unsigned short sB[2 * 128 * 32];
  const int tid = threadIdx.x;
  const int w = tid >> 6, lane = tid & 63;
  const int wr = w >> 1, wc = w & 1;
  const int bm = blockIdx.x, bn = blockIdx.y;
  const int fr = lane & 15;
  const int fg = lane >> 4;
  const int gsw = fg ^ ((fr >> 1) & 3);

  f32x4 acc[4][4];
#pragma unroll
  for (int i = 0; i < 4; i++)
#pragma unroll
    for (int j = 0; j < 4; j++) acc[i][j] = (f32x4){0.f, 0.f, 0.f, 0.f};

  const size_t arow = (size_t)bm * 128 * DIM;
  const size_t brow = (size_t)bn * 128 * DIM;
  const int sr_lo = tid >> 2;
  const int sg = (tid & 3) ^ ((tid >> 3) & 3);   // pre-swizzled source granule

  for (int kt = 0; kt < DIM; kt += 32) {
    __syncthreads();
#pragma unroll
    for (int h = 0; h < 2; h++) {
      const int r = h * 64 + sr_lo;
      const size_t asrc = arow + (size_t)r * DIM + kt + sg * 8;
      const size_t bsrc = brow + (size_t)r * DIM + kt + sg * 8;
      const int dofs = h * 2048 + w * 512;
      gload16(xhi + asrc, &sA[dofs]);
      gload16(xlo + asrc, &sA[4096 + dofs]);
      gload16(ghi + bsrc, &sB[dofs]);
      gload16(glo + bsrc, &sB[4096 + dofs]);
    }
    __syncthreads();

    short8v ah[4], al[4], bh[4], bl[4];
#pragma unroll
    for (int mf = 0; mf < 4; mf++) {
      int ro = (wr * 64 + mf * 16 + fr) * 32 + gsw * 8;
      ah[mf] = *(const short8v*)&sA[ro];
      al[mf] = *(const short8v*)&sA[4096 + ro];
    }
#pragma unroll
    for (int nf = 0; nf < 4; nf++) {
      int ro = (wc * 64 + nf * 16 + fr) * 32 + gsw * 8;
      bh[nf] = *(const short8v*)&sB[ro];
      bl[nf] = *(const short8v*)&sB[4096 + ro];
    }
#pragma unroll
    for (int mf = 0; mf < 4; mf++)
#pragma unroll
      for (int nf = 0; nf < 4; nf++) {
        f32x4 c = acc[mf][nf];
        c = __builtin_amdgcn_mfma_f32_16x16x32_bf16(ah[mf], bh[nf], c, 0, 0, 0);
        c = __builtin_amdgcn_mfma_f32_16x16x32_bf16(ah[mf], bl[nf], c, 0, 0, 0);
        c = __builtin_amdgcn_mfma_f32_16x16x32_bf16(al[mf], bh[nf], c, 0, 0, 0);
        acc[mf][nf] = c;
      }
  }

  // fused epilogue: bias + noise, per-token top-2 + expsum over this 64-col chunk
  const int gm0 = bm * 128 + wr * 64;
  const int gn0 = bn * 128 + wc * 64;
  const int chunk = bn * 2 + wc;   // 0..23
  int gcol[4]; float gbv[4];
#pragma unroll
  for (int nf = 0; nf < 4; nf++) { gcol[nf] = gn0 + nf * 16 + fr; gbv[nf] = gb[gcol[nf]]; }
#pragma unroll
  for (int mf = 0; mf < 4; mf++) {
    float sv[4][4];
#pragma unroll
    for (int nf = 0; nf < 4; nf++)
#pragma unroll
      for (int reg = 0; reg < 4; reg++) {
        int gm = gm0 + mf * 16 + fg * 4 + reg;
        sv[nf][reg] = acc[mf][nf][reg] + gbv[nf] + 0.1f * noise[(size_t)gm * NE + gcol[nf]];
      }
#pragma unroll
    for (int reg = 0; reg < 4; reg++) {
      float m1 = sv[0][reg]; int i1 = gcol[0];
      float m2 = -3e38f; int i2 = 0x7fffffff;
#pragma unroll
      for (int nf = 1; nf < 4; nf++) {
        float v = sv[nf][reg]; int ii = gcol[nf];
        if (v > m1 || (v == m1 && ii < i1)) { m2 = m1; i2 = i1; m1 = v; i1 = ii; }
        else if (v > m2 || (v == m2 && ii < i2)) { m2 = v; i2 = ii; }
      }
#pragma unroll
      for (int off = 1; off <= 8; off <<= 1) {
        float om1 = __shfl_xor(m1, off, 64); int oi1 = __shfl_xor(i1, off, 64);
        float om2 = __shfl_xor(m2, off, 64); int oi2 = __shfl_xor(i2, off, 64);
        top2_merge(m1, i1, m2, i2, om1, oi1, om2, oi2);
      }
      float ssum = 0.f;
#pragma unroll
      for (int nf = 0; nf < 4; nf++) ssum += __expf(sv[nf][reg] - m1);
#pragma unroll
      for (int off = 1; off <= 8; off <<= 1) ssum += __shfl_xor(ssum, off, 64);
      if (fr == 0) {
        int gm = gm0 + mf * 16 + fg * 4 + reg;
        part_a[(size_t)gm * 24 + chunk] = make_float4(m1, m2, ssum, __int_as_float(i1));
        part_i2[(size_t)gm * 24 + chunk] = i2;
      }
    }
  }
}

// ---- Kernel 2: merge 24 partials/token -> topw, idx, recheck flags ----
__global__ __launch_bounds__(256) void finalize(
    const float4* __restrict__ part_a, const int* __restrict__ part_i2,
    float* __restrict__ topw, int* __restrict__ idx,
    int* __restrict__ rc_count, int* __restrict__ rc_n, int* __restrict__ rc_i2) {
  const int wv = threadIdx.x >> 6, lane = threadIdx.x & 63;
  const int n = blockIdx.x * 4 + wv;
  float m1 = -3e38f, m2 = -3e38f, lm1 = -3e38f, lsum = 0.f;
  int i1 = 0x7fffffff, i2 = 0x7fffffff;
  if (lane < 24) {
    float4 pa = part_a[(size_t)n * 24 + lane];
    m1 = pa.x; m2 = pa.y; lsum = pa.z; i1 = __float_as_int(pa.w);
    i2 = part_i2[(size_t)n * 24 + lane];
    lm1 = pa.x;
  }
#pragma unroll
  for (int off = 1; off <= 32; off <<= 1) {
    float om1 = __shfl_xor(m1, off, 64); int oi1 = __shfl_xor(i1, off, 64);
    float om2 = __shfl_xor(m2, off, 64); int oi2 = __shfl_xor(i2, off, 64);
    top2_merge(m1, i1, m2, i2, om1, oi1, om2, oi2);
  }
  float contrib = (lane < 24) ? __expf(lm1 - m1) * lsum : 0.f;
#pragma unroll
  for (int off = 1; off <= 32; off <<= 1) contrib += __shfl_xor(contrib, off, 64);
  if (lane == 0) {
    topw[n] = 1.0f / contrib;
    idx[n] = i1;
    if (m1 - m2 < GAP_THR) {
      int p = atomicAdd(rc_count, 1);
      rc_n[p] = n; rc_i2[p] = i2;
    }
  }
}

// ---- Kernel 2b: fp32 exact recheck of near-tied top-2 (fixes idx only) ----
__global__ __launch_bounds__(256) void recheck(
    const float* __restrict__ x, const float* __restrict__ gw,
    const float* __restrict__ gb, const float* __restrict__ noise,
    const int* __restrict__ rc_n, const int* __restrict__ rc_i2,
    const int* __restrict__ rc_count, int* __restrict__ idx) {
  __shared__ float r1[4], r2[4];
  const int cnt = *rc_count;
  const int tid = threadIdx.x;
  const int w = tid >> 6, lane = tid & 63;
  for (int t = blockIdx.x; t < cnt; t += gridDim.x) {
    const int n = rc_n[t];
    const int e1 = idx[n], e2 = rc_i2[t];
    const float* xr = x + (size_t)n * DIM;
    const float* w1 = gw + (size_t)e1 * DIM;
    const float* w2 = gw + (size_t)e2 * DIM;
    float p1 = 0.f, p2 = 0.f;
    for (int k = tid; k < DIM; k += 256) {
      float xv = xr[k];
      p1 += xv * w1[k];
      p2 += xv * w2[k];
    }
#pragma unroll
    for (int off = 32; off; off >>= 1) {
      p1 += __shfl_xor(p1, off, 64);
      p2 += __shfl_xor(p2, off, 64);
    }
    if (lane == 0) { r1[w] = p1; r2[w] = p2; }
    __syncthreads();
    if (tid == 0) {
      float s1 = r1[0] + r1[1] + r1[2] + r1[3] + gb[e1] + 0.1f * noise[(size_t)n * NE + e1];
      float s2 = r2[0] + r2[1] + r2[2] + r2[3] + gb[e2] + 0.1f * noise[(size_t)n * NE + e2];
      if (s2 > s1 || (s2 == s1 && e2 < e1)) idx[n] = e2;
    }
    __syncthreads();
  }
}

// ---- Kernel 3: per-expert: self-select tokens, y = x·ewT+eb, out = (y·pwT+pb)*topw ----
// One block per expert. Scans idx (16KB, L2-resident), gathers its tokens, reads its
// 192KB weights once, projects directly to out (pw 196KB stays L2-resident).
__global__ __launch_bounds__(256) void expert_out(
    const float* __restrict__ x, const float* __restrict__ ew,
    const float* __restrict__ eb, const float* __restrict__ pw,
    const float* __restrict__ pb, const int* __restrict__ idx,
    const float* __restrict__ topw, float* __restrict__ out) {
  const int e = blockIdx.x;
  __shared__ int toklist[128];
  __shared__ int ntok_s;
  __shared__ float4 xs4[8 * 192];
  __shared__ __align__(16) float ys[8][64];
  __shared__ float tws[8];
  const int tid = threadIdx.x;
  const int w = tid >> 6;
  const int lane = tid & 63;

  if (tid == 0) ntok_s = 0;
  __syncthreads();
  // scan idx, compact tokens belonging to this expert
  for (int q = tid; q < NT / 4; q += 256) {
    int4 v = ((const int4*)idx)[q];
    int n0 = q * 4;
    if (v.x == e) { toklist[atomicAdd(&ntok_s, 1) & 127] = n0; }
    if (v.y == e) { toklist[atomicAdd(&ntok_s, 1) & 127] = n0 + 1; }
    if (v.z == e) { toklist[atomicAdd(&ntok_s, 1) & 127] = n0 + 2; }
    if (v.w == e) { toklist[atomicAdd(&ntok_s, 1) & 127] = n0 + 3; }
  }
  __syncthreads();
  const int cnt = ntok_s;   // realistically <= ~16
  if (cnt == 0) return;

  const float4* W4 = (const float4*)(ew + (size_t)e * ED * DIM);
  const float4* X4 = (const float4*)x;
  const float4* pw4 = (const float4*)pw;

  for (int c0 = 0; c0 < cnt; c0 += 8) {
    const int cc = min(8, cnt - c0);
    __syncthreads();  // protect xs4/ys/tws from previous iteration readers
    if (tid < cc) tws[tid] = topw[toklist[c0 + tid]];
    const int nf4 = cc * 192;
    for (int f = tid; f < nf4; f += 256) {
      int t = f / 192, p = f % 192;
      xs4[t * 192 + p] = X4[(size_t)toklist[c0 + t] * 192 + p];
    }
    __syncthreads();

    // y[t][o] for o = w*16 + oi
    for (int oi = 0; oi < 16; oi++) {
      int o = w * 16 + oi;
      float4 w4a = W4[(size_t)o * 192 + lane];
      float4 w4b = W4[(size_t)o * 192 + lane + 64];
      float4 w4c = W4[(size_t)o * 192 + lane + 128];
      for (int t = 0; t < cc; t++) {
        float4 xa = xs4[t * 192 + lane];
        float4 xb = xs4[t * 192 + lane + 64];
        float4 xc = xs4[t * 192 + lane + 128];
        float p = w4a.x * xa.x + w4a.y * xa.y + w4a.z * xa.z + w4a.w * xa.w;
        p += w4b.x * xb.x + w4b.y * xb.y + w4b.z * xb.z + w4b.w * xb.w;
        p += w4c.x * xc.x + w4c.y * xc.y + w4c.z * xc.z + w4c.w * xc.w;
#pragma unroll
        for (int off = 32; off; off >>= 1) p += __shfl_xor(p, off, 64);
        if (lane == 0) ys[t][o] = p + eb[e * ED + o];
      }
    }
    __syncthreads();

    // proj: out[n][d] = (sum_o ys[t][o]*pw[d][o] + pb[d]) * tw[t]
#pragma unroll
    for (int c = 0; c < 3; c++) {
      const int d = c * 256 + tid;
      float4 pwv[16];
#pragma unroll
      for (int q = 0; q < 16; q++) pwv[q] = pw4[(size_t)d * 16 + q];
      const float pbv = pb[d];
      for (int t = 0; t < cc; t++) {
        const float4* yv4 = (const float4*)ys[t];
        float s = 0.f;
#pragma unroll
        for (int q = 0; q < 16; q++) {
          float4 yv = yv4[q];
          s += pwv[q].x * yv.x + pwv[q].y * yv.y + pwv[q].z * yv.z + pwv[q].w * yv.w;
        }
        out[(size_t)toklist[c0 + t] * DIM + d] = (s + pbv) * tws[t];
      }
    }
  }
}

// ---------------- launch ----------------
extern "C" void kernel_launch(void* const* d_in, const int* in_sizes, int n_in,
                              void* d_out, int out_size, void* d_ws, size_t ws_size,
                              hipStream_t stream) {
  const float* x      = (const float*)d_in[0];
  const float* noise  = (const float*)d_in[1];
  const float* gate_w = (const float*)d_in[2];
  const float* gate_b = (const float*)d_in[3];
  const float* ew     = (const float*)d_in[4];
  const float* eb     = (const float*)d_in[5];
  const float* pw     = (const float*)d_in[6];
  const float* pb     = (const float*)d_in[7];
  float* out = (float*)d_out;

  char* ws = (char*)d_ws;
  unsigned short* xhi    = (unsigned short*)(ws);                // 6291456
  unsigned short* xlo    = (unsigned short*)(ws + 6291456);      // 6291456
  unsigned short* ghi    = (unsigned short*)(ws + 12582912);     // 2359296
  unsigned short* glo    = (unsigned short*)(ws + 14942208);     // 2359296
  float4*         part_a = (float4*)(ws + 17301504);             // 1572864
  int*            part_i2= (int*)  (ws + 18874368);              //  393216
  float*          topw   = (float*)(ws + 19267584);              //   16384
  int*            idx    = (int*)  (ws + 19283968);              //   16384
  int*            rc_cnt = (int*)  (ws + 19300352);              //     256
  int*            rc_n   = (int*)  (ws + 19300608);              //   16384
  int*            rc_i2  = (int*)  (ws + 19316992);              //   16384

  split_all<<<(NT * DIM / 4 + NE * DIM / 4 + 255) / 256, 256, 0, stream>>>(
      x, gate_w, xhi, xlo, ghi, glo, rc_cnt);
  gate_mfma<<<dim3(NT / 128, NE / 128), 256, 0, stream>>>(
      xhi, xlo, ghi, glo, gate_b, noise, part_a, part_i2);
  finalize<<<NT / 4, 256, 0, stream>>>(part_a, part_i2, topw, idx,
                                       rc_cnt, rc_n, rc_i2);
  recheck<<<32, 256, 0, stream>>>(x, gate_w, gate_b, noise, rc_n, rc_i2, rc_cnt, idx);
  expert_out<<<NE, 256, 0, stream>>>(x, ew, eb, pw, pb, idx, topw, out);
}

// Round 5
// 218.927 us; speedup vs baseline: 1.3877x; 1.3877x over previous
//
#include <hip/hip_runtime.h>
#include <hip/hip_bf16.h>

#define NT 4096      // tokens
#define DIM 768
#define NE 1536      // experts
#define ED 64        // expert dim
#define GAP_THR 8e-3f

typedef __attribute__((ext_vector_type(8))) short short8v;
typedef __attribute__((ext_vector_type(4))) float f32x4;

__device__ __forceinline__ unsigned short f2bf(float f) {
  unsigned int u = __float_as_uint(f);
  unsigned int r = (u + 0x7fffu + ((u >> 16) & 1u)) >> 16;   // RNE
  return (unsigned short)r;
}
__device__ __forceinline__ float bf2f(unsigned short h) {
  return __uint_as_float(((unsigned int)h) << 16);
}

__device__ __forceinline__ void gload16(const void* g, void* l) {
  __builtin_amdgcn_global_load_lds((const __attribute__((address_space(1))) void*)g,
                                   (__attribute__((address_space(3))) void*)l, 16, 0, 0);
}

__device__ __forceinline__ void top2_merge(float& m1, int& i1, float& m2, int& i2,
                                           float om1, int oi1, float om2, int oi2) {
  if (om1 > m1 || (om1 == m1 && oi1 < i1)) {
    if (m1 > om2 || (m1 == om2 && i1 < oi2)) { m2 = m1; i2 = i1; }
    else { m2 = om2; i2 = oi2; }
    m1 = om1; i1 = oi1;
  } else {
    if (om1 > m2 || (om1 == m2 && oi1 < i2)) { m2 = om1; i2 = oi1; }
  }
}

// ---- Kernel 0: fp32 -> (bf16 hi, bf16 lo) split (x and gate_w); zero rc_cnt ----
__global__ __launch_bounds__(256) void split_all(
    const float* __restrict__ x, const float* __restrict__ gw,
    unsigned short* __restrict__ xhi, unsigned short* __restrict__ xlo,
    unsigned short* __restrict__ ghi, unsigned short* __restrict__ glo,
    int* __restrict__ rc_cnt) {
  if (blockIdx.x == 0 && threadIdx.x == 0) *rc_cnt = 0;
  const int nx4 = NT * DIM / 4;
  const int ng4 = NE * DIM / 4;
  int i = blockIdx.x * 256 + threadIdx.x;
  const float* src; unsigned short* hi; unsigned short* lo; int j;
  if (i < nx4) { src = x; hi = xhi; lo = xlo; j = i; }
  else { j = i - nx4; if (j >= ng4) return; src = gw; hi = ghi; lo = glo; }
  float4 v = ((const float4*)src)[j];
  unsigned short h0 = f2bf(v.x), h1 = f2bf(v.y), h2 = f2bf(v.z), h3 = f2bf(v.w);
  ((ushort4*)hi)[j] = make_ushort4(h0, h1, h2, h3);
  ((ushort4*)lo)[j] = make_ushort4(f2bf(v.x - bf2f(h0)), f2bf(v.y - bf2f(h1)),
                                   f2bf(v.z - bf2f(h2)), f2bf(v.w - bf2f(h3)));
}

// ---- Kernel 1: gating GEMM (bf16x3 MFMA) + fused partial softmax ----
__global__ __launch_bounds__(256) void gate_mfma(
    const unsigned short* __restrict__ xhi, const unsigned short* __restrict__ xlo,
    const unsigned short* __restrict__ ghi, const unsigned short* __restrict__ glo,
    const float* __restrict__ gb, const float* __restrict__ noise,
    float4* __restrict__ part_a, int* __restrict__ part_i2) {
  __shared__ __align__(16) unsigned short sA[2 * 128 * 32];  // [0..4095]=hi, [4096..]=lo
  __shared__ __align__(16) unsigned short sB[2 * 128 * 32];
  const int tid = threadIdx.x;
  const int w = tid >> 6, lane = tid & 63;
  const int wr = w >> 1, wc = w & 1;
  const int bm = blockIdx.x, bn = blockIdx.y;
  const int fr = lane & 15;
  const int fg = lane >> 4;
  const int gsw = fg ^ ((fr >> 1) & 3);

  f32x4 acc[4][4];
#pragma unroll
  for (int i = 0; i < 4; i++)
#pragma unroll
    for (int j = 0; j < 4; j++) acc[i][j] = (f32x4){0.f, 0.f, 0.f, 0.f};

  const size_t arow = (size_t)bm * 128 * DIM;
  const size_t brow = (size_t)bn * 128 * DIM;
  const int sr_lo = tid >> 2;
  const int sg = (tid & 3) ^ ((tid >> 3) & 3);   // pre-swizzled source granule

  for (int kt = 0; kt < DIM; kt += 32) {
    __syncthreads();
#pragma unroll
    for (int h = 0; h < 2; h++) {
      const int r = h * 64 + sr_lo;
      const size_t asrc = arow + (size_t)r * DIM + kt + sg * 8;
      const size_t bsrc = brow + (size_t)r * DIM + kt + sg * 8;
      const int dofs = h * 2048 + w * 512;
      gload16(xhi + asrc, &sA[dofs]);
      gload16(xlo + asrc, &sA[4096 + dofs]);
      gload16(ghi + bsrc, &sB[dofs]);
      gload16(glo + bsrc, &sB[4096 + dofs]);
    }
    __syncthreads();

    short8v ah[4], al[4], bh[4], bl[4];
#pragma unroll
    for (int mf = 0; mf < 4; mf++) {
      int ro = (wr * 64 + mf * 16 + fr) * 32 + gsw * 8;
      ah[mf] = *(const short8v*)&sA[ro];
      al[mf] = *(const short8v*)&sA[4096 + ro];
    }
#pragma unroll
    for (int nf = 0; nf < 4; nf++) {
      int ro = (wc * 64 + nf * 16 + fr) * 32 + gsw * 8;
      bh[nf] = *(const short8v*)&sB[ro];
      bl[nf] = *(const short8v*)&sB[4096 + ro];
    }
#pragma unroll
    for (int mf = 0; mf < 4; mf++)
#pragma unroll
      for (int nf = 0; nf < 4; nf++) {
        f32x4 c = acc[mf][nf];
        c = __builtin_amdgcn_mfma_f32_16x16x32_bf16(ah[mf], bh[nf], c, 0, 0, 0);
        c = __builtin_amdgcn_mfma_f32_16x16x32_bf16(ah[mf], bl[nf], c, 0, 0, 0);
        c = __builtin_amdgcn_mfma_f32_16x16x32_bf16(al[mf], bh[nf], c, 0, 0, 0);
        acc[mf][nf] = c;
      }
  }

  // fused epilogue: bias + noise, per-token top-2 + expsum over this 64-col chunk
  const int gm0 = bm * 128 + wr * 64;
  const int gn0 = bn * 128 + wc * 64;
  const int chunk = bn * 2 + wc;   // 0..23
  int gcol[4]; float gbv[4];
#pragma unroll
  for (int nf = 0; nf < 4; nf++) { gcol[nf] = gn0 + nf * 16 + fr; gbv[nf] = gb[gcol[nf]]; }
#pragma unroll
  for (int mf = 0; mf < 4; mf++) {
    float sv[4][4];
#pragma unroll
    for (int nf = 0; nf < 4; nf++)
#pragma unroll
      for (int reg = 0; reg < 4; reg++) {
        int gm = gm0 + mf * 16 + fg * 4 + reg;
        sv[nf][reg] = acc[mf][nf][reg] + gbv[nf] + 0.1f * noise[(size_t)gm * NE + gcol[nf]];
      }
#pragma unroll
    for (int reg = 0; reg < 4; reg++) {
      float m1 = sv[0][reg]; int i1 = gcol[0];
      float m2 = -3e38f; int i2 = 0x7fffffff;
#pragma unroll
      for (int nf = 1; nf < 4; nf++) {
        float v = sv[nf][reg]; int ii = gcol[nf];
        if (v > m1 || (v == m1 && ii < i1)) { m2 = m1; i2 = i1; m1 = v; i1 = ii; }
        else if (v > m2 || (v == m2 && ii < i2)) { m2 = v; i2 = ii; }
      }
#pragma unroll
      for (int off = 1; off <= 8; off <<= 1) {
        float om1 = __shfl_xor(m1, off, 64); int oi1 = __shfl_xor(i1, off, 64);
        float om2 = __shfl_xor(m2, off, 64); int oi2 = __shfl_xor(i2, off, 64);
        top2_merge(m1, i1, m2, i2, om1, oi1, om2, oi2);
      }
      float ssum = 0.f;
#pragma unroll
      for (int nf = 0; nf < 4; nf++) ssum += __expf(sv[nf][reg] - m1);
#pragma unroll
      for (int off = 1; off <= 8; off <<= 1) ssum += __shfl_xor(ssum, off, 64);
      if (fr == 0) {
        int gm = gm0 + mf * 16 + fg * 4 + reg;
        part_a[(size_t)gm * 24 + chunk] = make_float4(m1, m2, ssum, __int_as_float(i1));
        part_i2[(size_t)gm * 24 + chunk] = i2;
      }
    }
  }
}

// ---- Kernel 2: merge 24 partials/token -> topw, idx, recheck flags ----
__global__ __launch_bounds__(256) void finalize(
    const float4* __restrict__ part_a, const int* __restrict__ part_i2,
    float* __restrict__ topw, int* __restrict__ idx,
    int* __restrict__ rc_count, int* __restrict__ rc_n, int* __restrict__ rc_i2) {
  const int wv = threadIdx.x >> 6, lane = threadIdx.x & 63;
  const int n = blockIdx.x * 4 + wv;
  float m1 = -3e38f, m2 = -3e38f, lm1 = -3e38f, lsum = 0.f;
  int i1 = 0x7fffffff, i2 = 0x7fffffff;
  if (lane < 24) {
    float4 pa = part_a[(size_t)n * 24 + lane];
    m1 = pa.x; m2 = pa.y; lsum = pa.z; i1 = __float_as_int(pa.w);
    i2 = part_i2[(size_t)n * 24 + lane];
    lm1 = pa.x;
  }
#pragma unroll
  for (int off = 1; off <= 32; off <<= 1) {
    float om1 = __shfl_xor(m1, off, 64); int oi1 = __shfl_xor(i1, off, 64);
    float om2 = __shfl_xor(m2, off, 64); int oi2 = __shfl_xor(i2, off, 64);
    top2_merge(m1, i1, m2, i2, om1, oi1, om2, oi2);
  }
  float contrib = (lane < 24) ? __expf(lm1 - m1) * lsum : 0.f;
#pragma unroll
  for (int off = 1; off <= 32; off <<= 1) contrib += __shfl_xor(contrib, off, 64);
  if (lane == 0) {
    topw[n] = 1.0f / contrib;
    idx[n] = i1;
    if (m1 - m2 < GAP_THR) {
      int p = atomicAdd(rc_count, 1);
      rc_n[p] = n; rc_i2[p] = i2;
    }
  }
}

// ---- Kernel 2b: fp32 exact recheck of near-tied top-2 (fixes idx only) ----
__global__ __launch_bounds__(256) void recheck(
    const float* __restrict__ x, const float* __restrict__ gw,
    const float* __restrict__ gb, const float* __restrict__ noise,
    const int* __restrict__ rc_n, const int* __restrict__ rc_i2,
    const int* __restrict__ rc_count, int* __restrict__ idx) {
  __shared__ float r1[4], r2[4];
  const int cnt = *rc_count;
  const int tid = threadIdx.x;
  const int w = tid >> 6, lane = tid & 63;
  for (int t = blockIdx.x; t < cnt; t += gridDim.x) {
    const int n = rc_n[t];
    const int e1 = idx[n], e2 = rc_i2[t];
    const float* xr = x + (size_t)n * DIM;
    const float* w1 = gw + (size_t)e1 * DIM;
    const float* w2 = gw + (size_t)e2 * DIM;
    float p1 = 0.f, p2 = 0.f;
    for (int k = tid; k < DIM; k += 256) {
      float xv = xr[k];
      p1 += xv * w1[k];
      p2 += xv * w2[k];
    }
#pragma unroll
    for (int off = 32; off; off >>= 1) {
      p1 += __shfl_xor(p1, off, 64);
      p2 += __shfl_xor(p2, off, 64);
    }
    if (lane == 0) { r1[w] = p1; r2[w] = p2; }
    __syncthreads();
    if (tid == 0) {
      float s1 = r1[0] + r1[1] + r1[2] + r1[3] + gb[e1] + 0.1f * noise[(size_t)n * NE + e1];
      float s2 = r2[0] + r2[1] + r2[2] + r2[3] + gb[e2] + 0.1f * noise[(size_t)n * NE + e2];
      if (s2 > s1 || (s2 == s1 && e2 < e1)) idx[n] = e2;
    }
    __syncthreads();
  }
}

// ---- Kernel 3: per-expert y = x·ewT + eb, streaming/shuffle-free ----
// One block per expert. W staged in 16KB chunks [64 out][64 d] (XOR-swizzled
// granules, pre-swizzled global source). Lane = (o_sub=lane&15, d_sub=lane>>4);
// wave w owns outputs w*16..w*16+15. W frag -> 16 VGPR once per chunk; per token
// 4 broadcast ds_read_b128 of x + 16 FMA. 2-shuffle reduce only at the end.
__global__ __launch_bounds__(256) void expert_y(
    const float* __restrict__ x, const float* __restrict__ ew,
    const float* __restrict__ eb, const int* __restrict__ idx,
    float* __restrict__ y) {
  const int e = blockIdx.x;
  __shared__ int toklist[128];
  __shared__ int ntok_s;
  __shared__ __align__(16) float Wl[64 * 64];    // 16 KB, [o][g^(o&7)] granules
  __shared__ __align__(16) float xs[8 * DIM];    // 24 KB
  const int tid = threadIdx.x;
  const int w = tid >> 6;
  const int lane = tid & 63;
  const int o_sub = lane & 15, d_sub = lane >> 4;
  const int o = w * 16 + o_sub;

  if (tid == 0) ntok_s = 0;
  __syncthreads();
  for (int q = tid; q < NT / 4; q += 256) {
    int4 v = ((const int4*)idx)[q];
    int n0 = q * 4;
    if (v.x == e) { toklist[atomicAdd(&ntok_s, 1) & 127] = n0; }
    if (v.y == e) { toklist[atomicAdd(&ntok_s, 1) & 127] = n0 + 1; }
    if (v.z == e) { toklist[atomicAdd(&ntok_s, 1) & 127] = n0 + 2; }
    if (v.w == e) { toklist[atomicAdd(&ntok_s, 1) & 127] = n0 + 3; }
  }
  __syncthreads();
  const int cnt = min(ntok_s, 128);
  if (cnt == 0) return;

  const float4* W4 = (const float4*)(ew + (size_t)e * ED * DIM);  // [64][192] f4
  const float4* X4 = (const float4*)x;

  for (int c0 = 0; c0 < cnt; c0 += 8) {
    const int cc = min(8, cnt - c0);
    __syncthreads();   // xs/Wl free (prev group done)
    // stage x for cc tokens: cc*192 float4, linear dest
    for (int k = 0; k < 6; k++) {
      int f = k * 256 + tid;
      if (f < cc * 192) {
        int t = f / 192, p = f - t * 192;
        gload16(&X4[(size_t)toklist[c0 + t] * 192 + p], &xs[f * 4]);
      }
    }

    float acc[8] = {};
    for (int ch = 0; ch < 12; ch++) {        // 12 chunks of 64 d
      // stage W chunk: 1024 float4; dest granule G=(o,g), src granule g^(o&7)
#pragma unroll
      for (int k = 0; k < 4; k++) {
        int G = k * 256 + tid;
        int ro = G >> 4, g = G & 15;
        gload16(&W4[(size_t)ro * 192 + ch * 16 + (g ^ (ro & 7))], &Wl[G * 4]);
      }
      __syncthreads();   // staging (x on first chunk, W always) complete

      f32x4 Wr[4];
#pragma unroll
      for (int j = 0; j < 4; j++)
        Wr[j] = *(const f32x4*)&Wl[(o * 16 + ((d_sub * 4 + j) ^ (o & 7))) * 4];
      __syncthreads();   // all waves got their W regs; LDS W free for next stage

      const int xbase = ch * 64 + d_sub * 16;
#pragma unroll
      for (int t = 0; t < 8; t++) {
        if (t < cc) {
#pragma unroll
          for (int j = 0; j < 4; j++) {
            f32x4 xv = *(const f32x4*)&xs[t * DIM + xbase + j * 4];
            acc[t] += Wr[j].x * xv.x + Wr[j].y * xv.y + Wr[j].z * xv.z + Wr[j].w * xv.w;
          }
        }
      }
    }

    const float ebv = eb[e * ED + w * 16 + o_sub];
#pragma unroll
    for (int t = 0; t < 8; t++) {
      if (t < cc) {
        float r = acc[t];
        r += __shfl_xor(r, 16, 64);
        r += __shfl_xor(r, 32, 64);
        if (lane < 16) y[(size_t)toklist[c0 + t] * ED + w * 16 + o_sub] = r + ebv;
      }
    }
  }
}

// ---- Kernel 4: projection + scale by top_w ----
__global__ __launch_bounds__(256) void proj_kernel(
    const float* __restrict__ y, const float* __restrict__ pw,
    const float* __restrict__ pb, const float* __restrict__ topw,
    float* __restrict__ out) {
  const int b = blockIdx.x;
  const int tid = threadIdx.x;
  __shared__ float4 ys4[8 * 16];
  __shared__ float tw[8];
  if (tid < 128) {
    int t = tid >> 4, q = tid & 15;
    ys4[tid] = ((const float4*)y)[((size_t)b * 8 + t) * 16 + q];
  }
  if (tid < 8) tw[tid] = topw[b * 8 + tid];
  __syncthreads();
  const float4* pw4 = (const float4*)pw;
#pragma unroll
  for (int c = 0; c < 3; c++) {
    int d = c * 256 + tid;
    float4 pwv[16];
#pragma unroll
    for (int q = 0; q < 16; q++) pwv[q] = pw4[(size_t)d * 16 + q];
    float pbv = pb[d];
    for (int t = 0; t < 8; t++) {
      const float4* yv4 = &ys4[t * 16];
      float s = 0.f;
#pragma unroll
      for (int q = 0; q < 16; q++) {
        float4 yv = yv4[q];
        s += pwv[q].x * yv.x + pwv[q].y * yv.y + pwv[q].z * yv.z + pwv[q].w * yv.w;
      }
      out[((size_t)b * 8 + t) * DIM + d] = (s + pbv) * tw[t];
    }
  }
}

// ---------------- launch ----------------
extern "C" void kernel_launch(void* const* d_in, const int* in_sizes, int n_in,
                              void* d_out, int out_size, void* d_ws, size_t ws_size,
                              hipStream_t stream) {
  const float* x      = (const float*)d_in[0];
  const float* noise  = (const float*)d_in[1];
  const float* gate_w = (const float*)d_in[2];
  const float* gate_b = (const float*)d_in[3];
  const float* ew     = (const float*)d_in[4];
  const float* eb     = (const float*)d_in[5];
  const float* pw     = (const float*)d_in[6];
  const float* pb     = (const float*)d_in[7];
  float* out = (float*)d_out;

  char* ws = (char*)d_ws;
  unsigned short* xhi    = (unsigned short*)(ws);                // 6291456
  unsigned short* xlo    = (unsigned short*)(ws + 6291456);      // 6291456
  unsigned short* ghi    = (unsigned short*)(ws + 12582912);     // 2359296
  unsigned short* glo    = (unsigned short*)(ws + 14942208);     // 2359296
  float4*         part_a = (float4*)(ws + 17301504);             // 1572864
  int*            part_i2= (int*)  (ws + 18874368);              //  393216
  float*          y      = (float*)(ws + 19267584);              // 1048576
  float*          topw   = (float*)(ws + 20316160);              //   16384
  int*            idx    = (int*)  (ws + 20332544);              //   16384
  int*            rc_cnt = (int*)  (ws + 20348928);              //     256
  int*            rc_n   = (int*)  (ws + 20349184);              //   16384
  int*            rc_i2  = (int*)  (ws + 20365568);              //   16384

  split_all<<<(NT * DIM / 4 + NE * DIM / 4 + 255) / 256, 256, 0, stream>>>(
      x, gate_w, xhi, xlo, ghi, glo, rc_cnt);
  gate_mfma<<<dim3(NT / 128, NE / 128), 256, 0, stream>>>(
      xhi, xlo, ghi, glo, gate_b, noise, part_a, part_i2);
  finalize<<<NT / 4, 256, 0, stream>>>(part_a, part_i2, topw, idx,
                                       rc_cnt, rc_n, rc_i2);
  recheck<<<32, 256, 0, stream>>>(x, gate_w, gate_b, noise, rc_n, rc_i2, rc_cnt, idx);
  expert_y<<<NE, 256, 0, stream>>>(x, ew, eb, idx, y);
  proj_kernel<<<NT / 8, 256, 0, stream>>>(y, pw, pb, topw, out);
}